// Round 4
// baseline (335.171 us; speedup 1.0000x reference)
//
#include <hip/hip_runtime.h>
#include <hip/hip_bf16.h>

// CTC forward loss, linear-domain DP with power-of-2 rescaling.
// k1: per (n,s) row: normalize probs, GATHER the 5 per-lane state probs,
//     write transposed planes: [(j0,j1) x64][(j2,j3) x64][j4 x64] = 320 f.
// k2: serial DP, 1 wave/batch. 5 states/lane. Conflict-free ds_read_b64/b32
//     (stride-1 lanes), 4-step register prefetch, 24-row DMA ring with
//     counted vmcnt(40). Cross-lane via DPP. No transcendentals in loop.
// k3: sum losses -> scalar.

#define S_LEN 1024
#define N_B   32
#define C_CLS 128
#define LOV   1e-5f
#define L2E   7.213475f            // 5 * log2(e)
#define E_M5  6.7379470e-03f       // e^-5
#define LN2   0.69314718f

#define ROW_F 320                  // floats per gathered row
#define RING  32                   // ring rows (40 KiB)
#define LEAD  24                   // staging lead, rows in flight
#define PFD   4                    // ds_read prefetch depth (steps)

__device__ __forceinline__ void dma16(const float* g, float* l) {
    __builtin_amdgcn_global_load_lds((const __attribute__((address_space(1))) void*)g,
                                     (__attribute__((address_space(3))) void*)l, 16, 0, 0);
}
__device__ __forceinline__ void dma4(const float* g, float* l) {
    __builtin_amdgcn_global_load_lds((const __attribute__((address_space(1))) void*)g,
                                     (__attribute__((address_space(3))) void*)l, 4, 0, 0);
}

// lane L receives x from lane L-1 (lane 0 garbage; caller overrides)
__device__ __forceinline__ int shl1_i(int x, bool row0lane) {
    int a = __builtin_amdgcn_update_dpp(0, x, 0x111, 0xf, 0xf, false); // row_shr:1
    int b = __builtin_amdgcn_update_dpp(0, x, 0x142, 0xf, 0xf, false); // row_bcast15
    return row0lane ? b : a;
}
__device__ __forceinline__ float shl1_f(float x, bool row0lane) {
    return __builtin_bit_cast(float, shl1_i(__builtin_bit_cast(int, x), row0lane));
}

// ---- kernel 1: normalize + gather + transpose ----------------------------
__global__ void __launch_bounds__(256)
ctc_pre_kernel(const float* __restrict__ inp, const int* __restrict__ lab,
               float* __restrict__ g, int chunk_start, int ch) {
    __shared__ float lp[4][C_CLS];
    const int wid  = threadIdx.x >> 6;
    const int lane = threadIdx.x & 63;
    const int W = blockIdx.x * 4 + wid;          // [0, 4*ch)
    const int n  = W & 31;
    const int sb = (W >> 5) * 8;                 // 8 rows per wave

    int offs[5];
    #pragma unroll
    for (int j = 0; j < 5; ++j) {
        int t = 5 * lane + j;
        int c = 0;
        if (t & 1) { int idx = (t - 1) >> 1; if (idx > 127) idx = 127; c = lab[idx * N_B + n]; }
        offs[j] = c << 2;
    }

    for (int r = 0; r < 8; ++r) {
        const int sl = sb + r;
        const int s  = chunk_start + sl;
        const float* row = inp + ((size_t)s * N_B + n) * C_CLS;
        float2 x = *(const float2*)(row + 2 * lane);
        float p0 = fmaxf(LOV, x.x), p1 = fmaxf(LOV, x.y);
        float sum = p0 + p1;
        #pragma unroll
        for (int off = 32; off; off >>= 1) sum += __shfl_xor(sum, off);
        float rinv = 1.0f / sum;
        float2 q2; q2.x = p0 * rinv; q2.y = p1 * rinv;
        *(float2*)&lp[wid][2 * lane] = q2;       // same-wave LDS: ordered
        const char* lpb = (const char*)&lp[wid][0];
        float g0 = *(const float*)(lpb + offs[0]);
        float g1 = *(const float*)(lpb + offs[1]);
        float g2 = *(const float*)(lpb + offs[2]);
        float g3 = *(const float*)(lpb + offs[3]);
        float g4 = *(const float*)(lpb + offs[4]);
        float* orow = g + ((size_t)n * ch + sl) * ROW_F;
        *(float2*)(orow + 2 * lane)       = make_float2(g0, g1);
        *(float2*)(orow + 128 + 2 * lane) = make_float2(g2, g3);
        orow[256 + lane] = g4;
    }
}

// ---- kernel 2: serial DP -------------------------------------------------
__global__ void __launch_bounds__(64)
ctc_dp_kernel(const float* __restrict__ g,
              const float* __restrict__ unused,
              float* __restrict__ vst,      // (N, 64, 6)
              float* __restrict__ losses,
              int chunk_start, int ch, int is_last) {
    __shared__ float ring[RING * ROW_F];     // 40 KiB
    const int n = blockIdx.x;
    const int lane = threadIdx.x;
    const bool row0lane = (lane & 15) == 0;
    const bool lane0 = (lane == 0);

    float u0, u1, u2, u3, u4; int ref;
    float* vr = vst + ((size_t)n * 64 + lane) * 6;
    if (chunk_start == 0) {
        ref = (int)(-36.067375f * (float)lane);
        u0 = exp2f(fmaf(-L2E, (float)(5 * lane + 0), -(float)ref));
        u1 = exp2f(fmaf(-L2E, (float)(5 * lane + 1), -(float)ref));
        u2 = exp2f(fmaf(-L2E, (float)(5 * lane + 2), -(float)ref));
        u3 = exp2f(fmaf(-L2E, (float)(5 * lane + 3), -(float)ref));
        u4 = exp2f(fmaf(-L2E, (float)(5 * lane + 4), -(float)ref));
    } else {
        u0 = vr[0]; u1 = vr[1]; u2 = vr[2]; u3 = vr[3]; u4 = vr[4];
        ref = __builtin_bit_cast(int, vr[5]);
    }

    const float* gn = g + (size_t)n * ch * ROW_F;

    // prologue: stage rows 0..LEAD-1 (48 vm-ops in flight)
    for (int r = 0; r < LEAD; ++r) {
        int sp = (r < ch) ? r : (ch - 1);
        const float* src = gn + (size_t)sp * ROW_F;
        float* dst = &ring[(r & (RING - 1)) * ROW_F];
        dma16(src + 4 * lane, dst);
        dma4(src + 256 + lane, dst + 256);
    }
    asm volatile("s_waitcnt vmcnt(40)" ::: "memory");   // rows 0..3 landed
    __builtin_amdgcn_sched_barrier(0);

    // register prefetch pipeline: pf[k] = row (i with i%4==k), depth 4
    float2 pA[PFD], pB[PFD]; float pC[PFD];
    #pragma unroll
    for (int k = 0; k < PFD; ++k) {
        const float* rp = &ring[k * ROW_F];
        pA[k] = *(const float2*)(rp + 2 * lane);
        pB[k] = *(const float2*)(rp + 128 + 2 * lane);
        pC[k] = rp[256 + lane];
    }

    const int ngroups = ch >> 2;
    for (int gi = 0; gi < ngroups; ++gi) {
        int refL = shl1_i(ref, row0lane);
        float fct = ldexpf(1.0f, refL - ref);
        float prev0 = exp2f(fmaf(-L2E, (float)(chunk_start + (gi << 2)), -(float)ref));
        #pragma unroll
        for (int k = 0; k < 4; ++k) {
            const int i = (gi << 2) + k;
            // stage row i+LEAD
            int sp = i + LEAD; if (sp >= ch) sp = ch - 1;
            const float* src = gn + (size_t)sp * ROW_F;
            float* dst = &ring[((i + LEAD) & (RING - 1)) * ROW_F];
            dma16(src + 4 * lane, dst);
            dma4(src + 256 + lane, dst + 256);
            // row i+PFD's 2 ops are the oldest beyond 2*(LEAD-PFD)=40 newer
            asm volatile("s_waitcnt vmcnt(40)" ::: "memory");
            __builtin_amdgcn_sched_barrier(0);
            // consume row i, refill pf[k] with row i+PFD
            float cq0 = pA[k].x, cq1 = pA[k].y, cq2 = pB[k].x,
                  cq3 = pB[k].y, cq4 = pC[k];
            const float* rp = &ring[((i + PFD) & (RING - 1)) * ROW_F];
            pA[k] = *(const float2*)(rp + 2 * lane);
            pB[k] = *(const float2*)(rp + 128 + 2 * lane);
            pC[k] = rp[256 + lane];
            // DP step
            float u4s  = shl1_f(u4, row0lane);
            float prev = lane0 ? prev0 : u4s * fct;
            float w0 = cq0 * (u0 + prev);
            float w1 = cq1 * (u1 + u0);
            float w2 = cq2 * (u2 + u1);
            float w3 = cq3 * (u3 + u2);
            float w4 = cq4 * (u4 + u3);
            u0 = w0; u1 = w1; u2 = w2; u3 = w3; u4 = w4;
            prev0 *= E_M5;
        }
        // per-lane power-of-2 rescale
        float M = fmaxf(fmaxf(fmaxf(u0, u1), fmaxf(u2, u3)), u4);
        int e = ((__builtin_bit_cast(int, M) >> 23) & 255) - 126;
        ref += e;
        u0 = ldexpf(u0, -e); u1 = ldexpf(u1, -e); u2 = ldexpf(u2, -e);
        u3 = ldexpf(u3, -e); u4 = ldexpf(u4, -e);
    }

    if (!is_last) {
        vr[0] = u0; vr[1] = u1; vr[2] = u2; vr[3] = u3; vr[4] = u4;
        vr[5] = __builtin_bit_cast(float, ref);
    } else if (lane == 51) {
        // u0 = state 255, u1 = state 256
        losses[n] = -(LN2 * (float)ref + __logf(u0 + u1));
    }
}

// ---- kernel 3: reduce ----------------------------------------------------
__global__ void ctc_sum_kernel(const float* __restrict__ losses,
                               float* __restrict__ out) {
    const int lane = threadIdx.x;
    float x = (lane < N_B) ? losses[lane] : 0.0f;
    #pragma unroll
    for (int off = 32; off; off >>= 1) x += __shfl_xor(x, off);
    if (lane == 0) out[0] = x / (float)N_B;
}

extern "C" void kernel_launch(void* const* d_in, const int* in_sizes, int n_in,
                              void* d_out, int out_size, void* d_ws, size_t ws_size,
                              hipStream_t stream) {
    const float* inp = (const float*)d_in[0];   // (S, N, C) f32
    const int*   lab = (const int*)d_in[1];     // (L, N) int32
    float* out = (float*)d_out;

    char* ws = (char*)d_ws;
    const size_t V_BYTES = (size_t)N_B * 64 * 6 * 4;              // 49152
    const size_t L_OFF = V_BYTES;
    const size_t M_OFF = (L_OFF + N_B * 4 + 511) & ~(size_t)511;  // 49664
    float* vst    = (float*)ws;
    float* losses = (float*)(ws + L_OFF);
    float* mbuf   = (float*)(ws + M_OFF);

    size_t usable = (ws_size > M_OFF) ? (ws_size - M_OFF) : 0;
    int CH = (int)(usable / ((size_t)N_B * ROW_F * 4));
    CH &= ~127;                       // multiple of 128
    if (CH > S_LEN) CH = S_LEN;
    if (CH < 128) CH = 128;

    for (int cs = 0; cs < S_LEN; cs += CH) {
        int ch = S_LEN - cs; if (ch > CH) ch = CH;
        ctc_pre_kernel<<<ch, 256, 0, stream>>>(inp, lab, mbuf, cs, ch);
        ctc_dp_kernel<<<N_B, 64, 0, stream>>>(mbuf, nullptr, vst, losses,
                                              cs, ch, (cs + ch >= S_LEN) ? 1 : 0);
    }
    ctc_sum_kernel<<<1, 64, 0, stream>>>(losses, out);
}

// Round 5
// 165.749 us; speedup vs baseline: 2.0222x; 2.0222x over previous
//
#include <hip/hip_runtime.h>
#include <hip/hip_bf16.h>

// CTC forward loss, linear-domain DP with power-of-2 rescaling.
// k1: per (n,s): normalize probs, gather 5 per-lane state probs, pack bf16
//     transposed row (640B): [(j0,j1)x64 lanes][(j2,j3)x64][j4 u16 x64].
// k2: serial DP, 1 wave/batch, NO LDS: rows loaded straight to registers
//     (2x b32 + 1x u16 per step, coalesced), 16-step register pipeline,
//     compile-time pf slots. DPP cross-lane, rescale every 4 steps.
// k3: sum losses -> scalar.

#define S_LEN 1024
#define N_B   32
#define C_CLS 128
#define LOV   1e-5f
#define L2E   7.213475f            // 5 * log2(e)
#define E_M5  6.7379470e-03f       // e^-5
#define LN2   0.69314718f

#define ROW_B 640                  // bytes per gathered bf16 row
#define PFD   16                   // register pipeline depth (steps)

typedef unsigned int  u32;
typedef unsigned short u16;

__device__ __forceinline__ u32 bf16r(float x) {   // f32 -> bf16 bits (RNE)
    u32 u = __builtin_bit_cast(u32, x);
    return (u + 0x7FFFu + ((u >> 16) & 1u)) >> 16;
}
__device__ __forceinline__ float bf_lo(u32 w) {   // low bf16 -> f32
    return __builtin_bit_cast(float, w << 16);
}
__device__ __forceinline__ float bf_hi(u32 w) {   // high bf16 -> f32
    return __builtin_bit_cast(float, w & 0xFFFF0000u);
}

// lane L receives x from lane L-1 (lane 0 garbage; caller overrides)
__device__ __forceinline__ int shl1_i(int x, bool row0lane) {
    int a = __builtin_amdgcn_update_dpp(0, x, 0x111, 0xf, 0xf, false); // row_shr:1
    int b = __builtin_amdgcn_update_dpp(0, x, 0x142, 0xf, 0xf, false); // row_bcast15
    return row0lane ? b : a;
}
__device__ __forceinline__ float shl1_f(float x, bool row0lane) {
    return __builtin_bit_cast(float, shl1_i(__builtin_bit_cast(int, x), row0lane));
}

// ---- kernel 1: normalize + gather + transpose + bf16 pack ----------------
__global__ void __launch_bounds__(256)
ctc_pre_kernel(const float* __restrict__ inp, const int* __restrict__ lab,
               unsigned char* __restrict__ g, int chunk_start, int ch) {
    __shared__ float lp[4][C_CLS];
    const int wid  = threadIdx.x >> 6;
    const int lane = threadIdx.x & 63;
    const int W = blockIdx.x * 4 + wid;          // [0, 4*ch)
    const int n  = W & 31;
    const int sb = (W >> 5) * 8;                 // 8 rows per wave

    int offs[5];
    #pragma unroll
    for (int j = 0; j < 5; ++j) {
        int t = 5 * lane + j;
        int c = 0;
        if (t & 1) { int idx = (t - 1) >> 1; if (idx > 127) idx = 127; c = lab[idx * N_B + n]; }
        offs[j] = c << 2;
    }

    for (int r = 0; r < 8; ++r) {
        const int sl = sb + r;
        const int s  = chunk_start + sl;
        const float* row = inp + ((size_t)s * N_B + n) * C_CLS;
        float2 x = *(const float2*)(row + 2 * lane);
        float p0 = fmaxf(LOV, x.x), p1 = fmaxf(LOV, x.y);
        float sum = p0 + p1;
        #pragma unroll
        for (int off = 32; off; off >>= 1) sum += __shfl_xor(sum, off);
        float rinv = 1.0f / sum;
        float2 q2; q2.x = p0 * rinv; q2.y = p1 * rinv;
        *(float2*)&lp[wid][2 * lane] = q2;       // same-wave LDS: ordered
        const char* lpb = (const char*)&lp[wid][0];
        float g0 = *(const float*)(lpb + offs[0]);
        float g1 = *(const float*)(lpb + offs[1]);
        float g2 = *(const float*)(lpb + offs[2]);
        float g3 = *(const float*)(lpb + offs[3]);
        float g4 = *(const float*)(lpb + offs[4]);
        unsigned char* orow = g + ((size_t)n * ch + sl) * ROW_B;
        *(u32*)(orow + 4 * lane)       = bf16r(g0) | (bf16r(g1) << 16);
        *(u32*)(orow + 256 + 4 * lane) = bf16r(g2) | (bf16r(g3) << 16);
        *(u16*)(orow + 512 + 2 * lane) = (u16)bf16r(g4);
    }
}

// ---- kernel 2: serial DP, register-pipelined, no LDS ---------------------
__global__ void __launch_bounds__(64)
ctc_dp_kernel(const unsigned char* __restrict__ g,
              float* __restrict__ vst,      // (N, 64, 6)
              float* __restrict__ losses,
              int chunk_start, int ch, int is_last) {
    const int n = blockIdx.x;
    const int lane = threadIdx.x;
    const bool row0lane = (lane & 15) == 0;
    const bool lane0 = (lane == 0);

    float u0, u1, u2, u3, u4; int ref;
    float* vr = vst + ((size_t)n * 64 + lane) * 6;
    if (chunk_start == 0) {
        ref = (int)(-36.067375f * (float)lane);
        u0 = exp2f(fmaf(-L2E, (float)(5 * lane + 0), -(float)ref));
        u1 = exp2f(fmaf(-L2E, (float)(5 * lane + 1), -(float)ref));
        u2 = exp2f(fmaf(-L2E, (float)(5 * lane + 2), -(float)ref));
        u3 = exp2f(fmaf(-L2E, (float)(5 * lane + 3), -(float)ref));
        u4 = exp2f(fmaf(-L2E, (float)(5 * lane + 4), -(float)ref));
    } else {
        u0 = vr[0]; u1 = vr[1]; u2 = vr[2]; u3 = vr[3]; u4 = vr[4];
        ref = __builtin_bit_cast(int, vr[5]);
    }

    const unsigned char* gn = g + (size_t)n * ch * ROW_B;
    const int oA = 4 * lane, oB = 256 + 4 * lane, oC = 512 + 2 * lane;

    // register pipeline: pf slot = step & 15 (all indices compile-time)
    u32 pfA[PFD], pfB[PFD], pfC[PFD];
    #pragma unroll
    for (int k = 0; k < PFD; ++k) {
        const unsigned char* rp = gn + (size_t)k * ROW_B;
        pfA[k] = *(const u32*)(rp + oA);
        pfB[k] = *(const u32*)(rp + oB);
        pfC[k] = *(const u16*)(rp + oC);
    }

    const int nblk = ch >> 4;
    for (int blk = 0; blk < nblk; ++blk) {
        const int i0 = blk << 4;
        #pragma unroll
        for (int q4 = 0; q4 < 4; ++q4) {
            // rescale-group constants (every 4 steps)
            int refL = shl1_i(ref, row0lane);
            float fct = ldexpf(1.0f, refL - ref);
            float prev0 = exp2f(fmaf(-L2E, (float)(chunk_start + i0 + 4 * q4),
                                     -(float)ref));
            #pragma unroll
            for (int k = 0; k < 4; ++k) {
                const int slot = q4 * 4 + k;          // 0..15 compile-time
                const int i = i0 + slot;
                // consume row i from pf[slot]
                float cq0 = bf_lo(pfA[slot]), cq1 = bf_hi(pfA[slot]);
                float cq2 = bf_lo(pfB[slot]), cq3 = bf_hi(pfB[slot]);
                float cq4 = __builtin_bit_cast(float, pfC[slot] << 16);
                // refill pf[slot] with row i+16 (clamped)
                int sp = i + PFD; if (sp > ch - 1) sp = ch - 1;
                const unsigned char* rp = gn + (size_t)sp * ROW_B;
                pfA[slot] = *(const u32*)(rp + oA);
                pfB[slot] = *(const u32*)(rp + oB);
                pfC[slot] = *(const u16*)(rp + oC);
                // DP step
                float u4s  = shl1_f(u4, row0lane);
                float prev = lane0 ? prev0 : u4s * fct;
                float w0 = cq0 * (u0 + prev);
                float w1 = cq1 * (u1 + u0);
                float w2 = cq2 * (u2 + u1);
                float w3 = cq3 * (u3 + u2);
                float w4 = cq4 * (u4 + u3);
                u0 = w0; u1 = w1; u2 = w2; u3 = w3; u4 = w4;
                prev0 *= E_M5;
            }
            // per-lane power-of-2 rescale
            float M = fmaxf(fmaxf(fmaxf(u0, u1), fmaxf(u2, u3)), u4);
            int e = ((__builtin_bit_cast(int, M) >> 23) & 255) - 126;
            ref += e;
            u0 = ldexpf(u0, -e); u1 = ldexpf(u1, -e); u2 = ldexpf(u2, -e);
            u3 = ldexpf(u3, -e); u4 = ldexpf(u4, -e);
        }
    }

    if (!is_last) {
        vr[0] = u0; vr[1] = u1; vr[2] = u2; vr[3] = u3; vr[4] = u4;
        vr[5] = __builtin_bit_cast(float, ref);
    } else if (lane == 51) {
        // u0 = state 255, u1 = state 256
        losses[n] = -(LN2 * (float)ref + __logf(u0 + u1));
    }
}

// ---- kernel 3: reduce ----------------------------------------------------
__global__ void ctc_sum_kernel(const float* __restrict__ losses,
                               float* __restrict__ out) {
    const int lane = threadIdx.x;
    float x = (lane < N_B) ? losses[lane] : 0.0f;
    #pragma unroll
    for (int off = 32; off; off >>= 1) x += __shfl_xor(x, off);
    if (lane == 0) out[0] = x / (float)N_B;
}

extern "C" void kernel_launch(void* const* d_in, const int* in_sizes, int n_in,
                              void* d_out, int out_size, void* d_ws, size_t ws_size,
                              hipStream_t stream) {
    const float* inp = (const float*)d_in[0];   // (S, N, C) f32
    const int*   lab = (const int*)d_in[1];     // (L, N) int32
    float* out = (float*)d_out;

    char* ws = (char*)d_ws;
    const size_t V_BYTES = (size_t)N_B * 64 * 6 * 4;              // 49152
    const size_t L_OFF = V_BYTES;
    const size_t M_OFF = (L_OFF + N_B * 4 + 511) & ~(size_t)511;  // 49664
    float* vst    = (float*)ws;
    float* losses = (float*)(ws + L_OFF);
    unsigned char* mbuf = (unsigned char*)(ws + M_OFF);

    size_t usable = (ws_size > M_OFF) ? (ws_size - M_OFF) : 0;
    int CH = (int)(usable / ((size_t)N_B * ROW_B));
    CH &= ~127;                       // multiple of 128
    if (CH > S_LEN) CH = S_LEN;
    if (CH < 128) CH = 128;

    for (int cs = 0; cs < S_LEN; cs += CH) {
        int ch = S_LEN - cs; if (ch > CH) ch = CH;
        ctc_pre_kernel<<<ch, 256, 0, stream>>>(inp, lab, mbuf, cs, ch);
        ctc_dp_kernel<<<N_B, 64, 0, stream>>>(mbuf, vst, losses,
                                              cs, ch, (cs + ch >= S_LEN) ? 1 : 0);
    }
    ctc_sum_kernel<<<1, 64, 0, stream>>>(losses, out);
}

// Round 7
// 144.900 us; speedup vs baseline: 2.3131x; 1.1439x over previous
//
#include <hip/hip_runtime.h>
#include <hip/hip_bf16.h>

// CTC forward loss, linear-domain DP with power-of-2 rescaling.
// k1 (wave-per-row): normalize probs, gather 5 per-lane state probs, write
//     f32 group-packed planes: per 4-step group (5120B):
//     [A01 1KB][A23 1KB][B01 1KB][B23 1KB][C 1KB], all lane*16 coalesced.
// k2: serial DP, 1 wave/batch. 5 states/lane (t=5*lane+j). Loads forced into
//     an 8-group inline-asm pipeline (5x dwordx4 per group), counted
//     s_waitcnt vmcnt(35) + sched_barrier(0) (rule #18 recipe). DPP
//     cross-lane, power-of-2 rescale every 4 steps. No transcendentals on
//     the chain.
// k3: sum losses -> scalar.

#define S_LEN 1024
#define N_B   32
#define C_CLS 128
#define LOV   1e-5f
#define L2E   7.213475f            // 5 * log2(e)
#define E_M5  6.7379470e-03f       // e^-5
#define LN2   0.69314718f

#define GRP_B  5120                // bytes per 4-step group
#define G_PIPE 8                   // groups in flight

// lane L receives x from lane L-1 (lane 0 garbage; caller overrides)
__device__ __forceinline__ int shl1_i(int x, bool row0lane) {
    int a = __builtin_amdgcn_update_dpp(0, x, 0x111, 0xf, 0xf, false); // row_shr:1
    int b = __builtin_amdgcn_update_dpp(0, x, 0x142, 0xf, 0xf, false); // row_bcast15
    return row0lane ? b : a;
}
__device__ __forceinline__ float shl1_f(float x, bool row0lane) {
    return __builtin_bit_cast(float, shl1_i(__builtin_bit_cast(int, x), row0lane));
}

#define ISSUE_GROUP(sidx, rp)                                                  \
    do {                                                                       \
        const char* _rp = (rp);                                                \
        const char* _rpC = _rp + 4096;                                         \
        asm volatile(                                                          \
            "global_load_dwordx4 %0, %5, %6 offset:0\n\t"                      \
            "global_load_dwordx4 %1, %5, %6 offset:1024\n\t"                   \
            "global_load_dwordx4 %2, %5, %6 offset:2048\n\t"                   \
            "global_load_dwordx4 %3, %5, %6 offset:3072\n\t"                   \
            "global_load_dwordx4 %4, %5, %7 offset:0"                          \
            : "=v"(A1[sidx]), "=v"(A2[sidx]), "=v"(B1[sidx]),                  \
              "=v"(B2[sidx]), "=v"(C4[sidx])                                   \
            : "v"(lane16), "s"(_rp), "s"(_rpC)                                 \
            : "memory");                                                       \
    } while (0)

// ---- kernel 1: normalize + gather + group-packed f32 planes --------------
__global__ void __launch_bounds__(256)
ctc_pre_kernel(const float* __restrict__ inp, const int* __restrict__ lab,
               float* __restrict__ gbuf, int chunk_start, int ch) {
    __shared__ float lp[4][C_CLS];
    const int wid  = threadIdx.x >> 6;
    const int lane = threadIdx.x & 63;
    const int R = blockIdx.x * 4 + wid;          // [0, ch*N_B)
    const int n  = R & 31;
    const int sl = R >> 5;
    const int s  = chunk_start + sl;

    int offs[5];
    #pragma unroll
    for (int j = 0; j < 5; ++j) {
        int t = 5 * lane + j;
        int c = 0;
        if (t & 1) { int idx = (t - 1) >> 1; if (idx > 127) idx = 127; c = lab[idx * N_B + n]; }
        offs[j] = c << 2;
    }

    const float* row = inp + ((size_t)s * N_B + n) * C_CLS;
    float2 x = *(const float2*)(row + 2 * lane);
    float p0 = fmaxf(LOV, x.x), p1 = fmaxf(LOV, x.y);
    float sum = p0 + p1;
    #pragma unroll
    for (int off = 32; off; off >>= 1) sum += __shfl_xor(sum, off);
    float rinv = 1.0f / sum;
    *(float2*)&lp[wid][2 * lane] = make_float2(p0 * rinv, p1 * rinv);
    const char* lpb = (const char*)&lp[wid][0];   // same-wave LDS: ordered
    float g0 = *(const float*)(lpb + offs[0]);
    float g1 = *(const float*)(lpb + offs[1]);
    float g2 = *(const float*)(lpb + offs[2]);
    float g3 = *(const float*)(lpb + offs[3]);
    float g4 = *(const float*)(lpb + offs[4]);

    const int g = sl >> 2, k = sl & 3;
    float* base = gbuf + ((size_t)n * (ch >> 2) + g) * (GRP_B / 4);
    const int half = (k >> 1) * 256, odd = (k & 1) * 2;
    *(float2*)(base + half + lane * 4 + odd)       = make_float2(g0, g1);
    *(float2*)(base + 512 + half + lane * 4 + odd) = make_float2(g2, g3);
    base[1024 + lane * 4 + k] = g4;
}

// ---- kernel 2: serial DP, asm-pipelined loads ----------------------------
__global__ void __launch_bounds__(64)
ctc_dp_kernel(const float* __restrict__ gbuf,
              float* __restrict__ vst,      // (N, 64, 6)
              float* __restrict__ losses,
              int chunk_start, int ch, int is_last) {
    const int n = blockIdx.x;
    const int lane = threadIdx.x;
    const bool row0lane = (lane & 15) == 0;
    const bool lane0 = (lane == 0);
    const unsigned lane16 = lane * 16;

    float u0, u1, u2, u3, u4; int ref;
    float* vr = vst + ((size_t)n * 64 + lane) * 6;
    if (chunk_start == 0) {
        ref = (int)(-36.067375f * (float)lane);
        u0 = exp2f(fmaf(-L2E, (float)(5 * lane + 0), -(float)ref));
        u1 = exp2f(fmaf(-L2E, (float)(5 * lane + 1), -(float)ref));
        u2 = exp2f(fmaf(-L2E, (float)(5 * lane + 2), -(float)ref));
        u3 = exp2f(fmaf(-L2E, (float)(5 * lane + 3), -(float)ref));
        u4 = exp2f(fmaf(-L2E, (float)(5 * lane + 4), -(float)ref));
    } else {
        u0 = vr[0]; u1 = vr[1]; u2 = vr[2]; u3 = vr[3]; u4 = vr[4];
        ref = __builtin_bit_cast(int, vr[5]);
    }

    const int ng = ch >> 2;
    const char* nbase = (const char*)(gbuf + (size_t)n * ng * (GRP_B / 4));

    float4 A1[G_PIPE], A2[G_PIPE], B1[G_PIPE], B2[G_PIPE], C4[G_PIPE];

    // prologue: 8 groups (40 loads) in flight
    #pragma unroll
    for (int sidx = 0; sidx < G_PIPE; ++sidx)
        ISSUE_GROUP(sidx, nbase + (size_t)sidx * GRP_B);

    for (int g0 = 0; g0 < ng; g0 += G_PIPE) {
        #pragma unroll
        for (int sidx = 0; sidx < G_PIPE; ++sidx) {
            const int g = g0 + sidx;
            // group g's 5 loads are the oldest; 7 newer groups = 35 ops.
            // rule #18: plain waitcnt + sched_barrier fence, no tied operands.
            asm volatile("s_waitcnt vmcnt(35)" ::: "memory");
            __builtin_amdgcn_sched_barrier(0);
            float4 a1 = A1[sidx], a2 = A2[sidx];
            float4 b1 = B1[sidx], b2 = B2[sidx], c4 = C4[sidx];

            // group constants
            int refL = shl1_i(ref, row0lane);
            float fct = ldexpf(1.0f, refL - ref);
            float prev0 = exp2f(fmaf(-L2E, (float)(chunk_start + 4 * g),
                                     -(float)ref));
            #pragma unroll
            for (int k = 0; k < 4; ++k) {
                float cq0, cq1, cq2, cq3, cq4;
                if (k == 0)      { cq0=a1.x; cq1=a1.y; cq2=b1.x; cq3=b1.y; cq4=c4.x; }
                else if (k == 1) { cq0=a1.z; cq1=a1.w; cq2=b1.z; cq3=b1.w; cq4=c4.y; }
                else if (k == 2) { cq0=a2.x; cq1=a2.y; cq2=b2.x; cq3=b2.y; cq4=c4.z; }
                else             { cq0=a2.z; cq1=a2.w; cq2=b2.z; cq3=b2.w; cq4=c4.w; }
                float u4s  = shl1_f(u4, row0lane);
                float prev = lane0 ? prev0 : u4s * fct;
                float w0 = cq0 * (u0 + prev);
                float w1 = cq1 * (u1 + u0);
                float w2 = cq2 * (u2 + u1);
                float w3 = cq3 * (u3 + u2);
                float w4 = cq4 * (u4 + u3);
                u0 = w0; u1 = w1; u2 = w2; u3 = w3; u4 = w4;
                prev0 *= E_M5;
            }
            // per-lane power-of-2 rescale
            float M = fmaxf(fmaxf(fmaxf(u0, u1), fmaxf(u2, u3)), u4);
            int e = ((__builtin_bit_cast(int, M) >> 23) & 255) - 126;
            ref += e;
            u0 = ldexpf(u0, -e); u1 = ldexpf(u1, -e); u2 = ldexpf(u2, -e);
            u3 = ldexpf(u3, -e); u4 = ldexpf(u4, -e);

            // refill slot with group g+G_PIPE (clamped; redundant loads OK)
            int sp = g + G_PIPE; if (sp > ng - 1) sp = ng - 1;
            ISSUE_GROUP(sidx, nbase + (size_t)sp * GRP_B);
        }
    }
    // drain outstanding prefetches before leaving
    asm volatile("s_waitcnt vmcnt(0)" ::: "memory");

    if (!is_last) {
        vr[0] = u0; vr[1] = u1; vr[2] = u2; vr[3] = u3; vr[4] = u4;
        vr[5] = __builtin_bit_cast(float, ref);
    } else if (lane == 51) {
        // u0 = state 255, u1 = state 256
        losses[n] = -(LN2 * (float)ref + __logf(u0 + u1));
    }
}

// ---- kernel 3: reduce ----------------------------------------------------
__global__ void ctc_sum_kernel(const float* __restrict__ losses,
                               float* __restrict__ out) {
    const int lane = threadIdx.x;
    float x = (lane < N_B) ? losses[lane] : 0.0f;
    #pragma unroll
    for (int off = 32; off; off >>= 1) x += __shfl_xor(x, off);
    if (lane == 0) out[0] = x / (float)N_B;
}

extern "C" void kernel_launch(void* const* d_in, const int* in_sizes, int n_in,
                              void* d_out, int out_size, void* d_ws, size_t ws_size,
                              hipStream_t stream) {
    const float* inp = (const float*)d_in[0];   // (S, N, C) f32
    const int*   lab = (const int*)d_in[1];     // (L, N) int32
    float* out = (float*)d_out;

    char* ws = (char*)d_ws;
    const size_t V_BYTES = (size_t)N_B * 64 * 6 * 4;              // 49152
    const size_t L_OFF = V_BYTES;
    const size_t M_OFF = (L_OFF + N_B * 4 + 511) & ~(size_t)511;  // 49664
    float* vst    = (float*)ws;
    float* losses = (float*)(ws + L_OFF);
    float* mbuf   = (float*)(ws + M_OFF);

    // bytes per step across batch: N_B * GRP_B/4 = 40960
    size_t usable = (ws_size > M_OFF) ? (ws_size - M_OFF) : 0;
    int CH = (int)(usable / ((size_t)N_B * (GRP_B / 4)));
    CH &= ~127;                       // multiple of 128 (=> groups % 8 == 0)
    if (CH > S_LEN) CH = S_LEN;
    if (CH < 128) CH = 128;

    for (int cs = 0; cs < S_LEN; cs += CH) {
        int ch = S_LEN - cs; if (ch > CH) ch = CH;
        ctc_pre_kernel<<<ch * N_B / 4, 256, 0, stream>>>(inp, lab, mbuf, cs, ch);
        ctc_dp_kernel<<<N_B, 64, 0, stream>>>(mbuf, vst, losses,
                                              cs, ch, (cs + ch >= S_LEN) ? 1 : 0);
    }
    ctc_sum_kernel<<<1, 64, 0, stream>>>(losses, out);
}